// Round 1
// 322.084 us; speedup vs baseline: 1.0238x; 1.0238x over previous
//
#include <hip/hip_runtime.h>
#include <stdint.h>

typedef unsigned short u16;
typedef __attribute__((ext_vector_type(8))) _Float16 half8;  // 8 x f16 (4 VGPRs)
typedef __attribute__((ext_vector_type(4))) float f32x4;

#define L2E 1.4426950408889634f

// B=4, T=2048, D=512, H=8, DK=64; NTOK = B*T = 8192
#define NTOK 8192
#define DIM  512
#define TT   2048

__device__ __forceinline__ u16 f2h(float f) {
  _Float16 h = (_Float16)f;  // RNE via v_cvt_f16_f32
  return __builtin_bit_cast(u16, h);
}

__device__ __forceinline__ void async16(const void* g, void* l) {
  __builtin_amdgcn_global_load_lds(
      (const __attribute__((address_space(1))) unsigned int*)g,
      (__attribute__((address_space(3))) unsigned int*)l, 16, 0, 0);
}

// ---------------- fp32 -> fp16 conversion: x (4.19M) + 4 weights (262144 each)
__global__ __launch_bounds__(256) void k_convert(
    const float* __restrict__ x, const float* __restrict__ wq,
    const float* __restrict__ wk, const float* __restrict__ wv,
    const float* __restrict__ wo, u16* __restrict__ xb) {
  size_t i = ((size_t)blockIdx.x * 256 + threadIdx.x) * 8;
  const float* src;
  u16* dst;
  size_t off;
  if (i < 4194304) {
    src = x; dst = xb; off = i;
  } else {
    size_t j = i - 4194304;
    int w = (int)(j >> 18);
    off = j & 262143;
    src = (w == 0) ? wq : (w == 1) ? wk : (w == 2) ? wv : wo;
    dst = xb + 4194304 + (size_t)w * 262144;
  }
  float4 a = *(const float4*)(src + off);
  float4 b = *(const float4*)(src + off + 4);
  uint4 pk;
  pk.x = (unsigned)f2h(a.x) | ((unsigned)f2h(a.y) << 16);
  pk.y = (unsigned)f2h(a.z) | ((unsigned)f2h(a.w) << 16);
  pk.z = (unsigned)f2h(b.x) | ((unsigned)f2h(b.y) << 16);
  pk.w = (unsigned)f2h(b.z) | ((unsigned)f2h(b.w) << 16);
  *(uint4*)(dst + off) = pk;
}

// ---------------- QKV projection GEMM, 128x128 tiles: C = x @ W^T
// VSWAP=false (Q,K): D[token][feat] -> head-major [bh][t][dk]
// VSWAP=true  (V)  : MFMA operands swapped -> D[feat][token] -> Vt [bh][dk][t]
template <bool VSWAP>
__global__ __launch_bounds__(256) void k_proj(
    const u16* __restrict__ A, const u16* __restrict__ Wb,
    u16* __restrict__ Db) {
  const int tid = threadIdx.x;
  const int wave = tid >> 6, lane = tid & 63;
  const int quad = lane >> 4, l16 = lane & 15;
  const int wr = wave >> 1, wc = wave & 1;
  const int m0 = blockIdx.x * 128, n0 = blockIdx.y * 128;

  const u16* W;
  u16* D;
  if (VSWAP) {
    W = Wb + 2 * 262144;            // Wv
    D = Db + 2 * (size_t)4194304;   // Vt
  } else {
    int z = blockIdx.z;
    W = Wb + (size_t)z * 262144;    // Wq / Wk
    D = Db + (size_t)z * 4194304;   // Q / K head-major
  }

  __shared__ __align__(16) u16 As[128 * 64];
  __shared__ __align__(16) u16 Bs[128 * 64];

  f32x4 acc[4][4];
  for (int rt = 0; rt < 4; ++rt)
    for (int ct = 0; ct < 4; ++ct) acc[rt][ct] = (f32x4){0.f, 0.f, 0.f, 0.f};

  for (int kb = 0; kb < 8; ++kb) {
    const int k0 = kb * 64;
    for (int r = 0; r < 4; ++r) {
      int cid = r * 256 + tid;
      int row = cid >> 3, cl = cid & 7, cg = cl ^ (row & 7);
      async16(A + (size_t)(m0 + row) * DIM + k0 + cg * 8,
              &As[(r * 256 + wave * 64) * 8]);
    }
    for (int r = 0; r < 4; ++r) {
      int cid = r * 256 + tid;
      int row = cid >> 3, cl = cid & 7, cg = cl ^ (row & 7);
      async16(W + (size_t)(n0 + row) * DIM + k0 + cg * 8,
              &Bs[(r * 256 + wave * 64) * 8]);
    }
    __syncthreads();
    for (int kc = 0; kc < 2; ++kc) {
      half8 af[4], wf[4];
      for (int rt = 0; rt < 4; ++rt) {
        int row = wr * 64 + rt * 16 + l16;
        int c = (kc * 4 + quad) ^ (row & 7);
        af[rt] = *(const half8*)&As[row * 64 + c * 8];
      }
      for (int ct = 0; ct < 4; ++ct) {
        int row = wc * 64 + ct * 16 + l16;
        int c = (kc * 4 + quad) ^ (row & 7);
        wf[ct] = *(const half8*)&Bs[row * 64 + c * 8];
      }
      for (int rt = 0; rt < 4; ++rt)
        for (int ct = 0; ct < 4; ++ct)
          acc[rt][ct] = VSWAP
              ? __builtin_amdgcn_mfma_f32_16x16x32_f16(wf[ct], af[rt],
                                                       acc[rt][ct], 0, 0, 0)
              : __builtin_amdgcn_mfma_f32_16x16x32_f16(af[rt], wf[ct],
                                                       acc[rt][ct], 0, 0, 0);
    }
    __syncthreads();
  }

  // C/D layout: col = lane&15, row = quad*4 + reg.
  for (int rt = 0; rt < 4; ++rt)
    for (int ct = 0; ct < 4; ++ct)
      for (int reg = 0; reg < 4; ++reg) {
        float v = acc[rt][ct][reg];
        if (!VSWAP) {
          int gm = m0 + wr * 64 + rt * 16 + quad * 4 + reg;  // token
          int gn = n0 + wc * 64 + ct * 16 + l16;             // feature
          int bb = gm >> 11, t = gm & 2047, hh = gn >> 6, dk = gn & 63;
          D[(((size_t)(bb * 8 + hh) * TT + t) << 6) + dk] = f2h(v);
        } else {
          int feat = n0 + wc * 64 + ct * 16 + quad * 4 + reg;  // m-dim = feature
          int tok  = m0 + wr * 64 + rt * 16 + l16;             // n-dim = token
          int bb = tok >> 11, t = tok & 2047, hh = feat >> 6, dk = feat & 63;
          D[(((size_t)(bb * 8 + hh) << 6) + dk) * TT + t] = f2h(v);
        }
      }
}

// ---------------- output GEMM: out = y @ Wo^T, 64x128 tiles, fp32 out
__global__ __launch_bounds__(256) void k_ogemm(
    const u16* __restrict__ A, const u16* __restrict__ W,
    float* __restrict__ Df) {
  const int tid = threadIdx.x;
  const int wave = tid >> 6, lane = tid & 63;
  const int quad = lane >> 4, l16 = lane & 15;
  const int wr = wave >> 1, wc = wave & 1;
  const int m0 = blockIdx.x * 64, n0 = blockIdx.y * 128;

  __shared__ __align__(16) u16 As[64 * 64];
  __shared__ __align__(16) u16 Bs[128 * 64];

  f32x4 acc[2][4];
  for (int rt = 0; rt < 2; ++rt)
    for (int ct = 0; ct < 4; ++ct) acc[rt][ct] = (f32x4){0.f, 0.f, 0.f, 0.f};

  for (int kb = 0; kb < 8; ++kb) {
    const int k0 = kb * 64;
    for (int r = 0; r < 2; ++r) {
      int cid = r * 256 + tid;
      int row = cid >> 3, cl = cid & 7, cg = cl ^ (row & 7);
      async16(A + (size_t)(m0 + row) * DIM + k0 + cg * 8,
              &As[(r * 256 + wave * 64) * 8]);
    }
    for (int r = 0; r < 4; ++r) {
      int cid = r * 256 + tid;
      int row = cid >> 3, cl = cid & 7, cg = cl ^ (row & 7);
      async16(W + (size_t)(n0 + row) * DIM + k0 + cg * 8,
              &Bs[(r * 256 + wave * 64) * 8]);
    }
    __syncthreads();
    for (int kc = 0; kc < 2; ++kc) {
      half8 af[2], wf[4];
      for (int rt = 0; rt < 2; ++rt) {
        int row = wr * 32 + rt * 16 + l16;
        int c = (kc * 4 + quad) ^ (row & 7);
        af[rt] = *(const half8*)&As[row * 64 + c * 8];
      }
      for (int ct = 0; ct < 4; ++ct) {
        int row = wc * 64 + ct * 16 + l16;
        int c = (kc * 4 + quad) ^ (row & 7);
        wf[ct] = *(const half8*)&Bs[row * 64 + c * 8];
      }
      for (int rt = 0; rt < 2; ++rt)
        for (int ct = 0; ct < 4; ++ct)
          acc[rt][ct] = __builtin_amdgcn_mfma_f32_16x16x32_f16(
              af[rt], wf[ct], acc[rt][ct], 0, 0, 0);
    }
    __syncthreads();
  }

  for (int rt = 0; rt < 2; ++rt)
    for (int ct = 0; ct < 4; ++ct)
      for (int reg = 0; reg < 4; ++reg) {
        int gm = m0 + wr * 32 + rt * 16 + quad * 4 + reg;
        int gn = n0 + wc * 64 + ct * 16 + l16;
        Df[(size_t)gm * DIM + gn] = acc[rt][ct][reg];
      }
}

// ---------------- flash attention: 1024 blocks = 32 bh * 32 q-tiles(64 rows)
// Both MFMAs use SWAPPED operands: mfma(K,Q) and mfma(V,P), so the output
// column (=l16) is the q-row for both S and O. Softmax stats (m,l,alpha)
// become lane-local scalars; bias/mask gathers become float4 vector loads.
__global__ __launch_bounds__(256, 4) void k_attn(
    const u16* __restrict__ Q, const u16* __restrict__ K,
    const u16* __restrict__ Vt, const float* __restrict__ bias,
    const float* __restrict__ mask, u16* __restrict__ Y) {
  const int tid = threadIdx.x;
  const int wv = tid >> 6;
  const int lane = tid & 63;
  const int quad = lane >> 4;
  const int l16 = lane & 15;

  const int bx = blockIdx.x;
  const int bh = bx >> 5;  // 0..31
  const int qt = bx & 31;
  const int b = bh >> 3, h = bh & 7;
  const int q0 = qt * 64;

  __shared__ __align__(16) u16 Ks[64 * 64];  // K tile [s][dk]
  __shared__ __align__(16) u16 Vs[64 * 64];  // V^T tile [dk][s]
  __shared__ __align__(16) u16 Pl[64 * 72];  // P [q][s], padded stride 72

  // Q fragments (B-operand: n = l16 = q-row, k = quad*8+j). Wave wv owns
  // q rows q0 + wv*16 .. +15; each lane carries exactly one q-row.
  const int qrow = q0 + wv * 16 + l16;
  half8 qf[2];
  {
    size_t qoff = ((size_t)bh * TT + qrow) * 64;
    qf[0] = *(const half8*)(Q + qoff + quad * 8);
    qf[1] = *(const half8*)(Q + qoff + 32 + quad * 8);
  }

  // Per-lane s positions within a tile: s = s0 + ct*16 + quad*4 + reg
  // -> bias/mask are 4 consecutive floats per ct: float4 loads.
  const float* brow = bias + (size_t)h * TT * TT + (size_t)qrow * TT + quad * 4;
  const float* mrow = mask + (size_t)b * TT + quad * 4;

  float m_i = -1e30f, l_i = 0.f;
  f32x4 oacc[4];
  for (int ct = 0; ct < 4; ++ct) oacc[ct] = (f32x4){0.f, 0.f, 0.f, 0.f};

  // Bias prefetch for tile 0 (one tile ahead thereafter).
  f32x4 bL[4];
  for (int ct = 0; ct < 4; ++ct) bL[ct] = *(const f32x4*)(brow + ct * 16);

  for (int st = 0; st < 32; ++st) {
    const int s0 = st * 64;
    // stage K (s-major) and V^T (dk-major) tiles via global_load_lds
    for (int r = 0; r < 2; ++r) {
      int cid = r * 256 + tid;
      int row = cid >> 3, cl = cid & 7, cg = cl ^ (row & 7);
      async16(K + ((size_t)bh * TT + s0 + row) * 64 + cg * 8,
              &Ks[(r * 256 + wv * 64) * 8]);
      async16(Vt + ((size_t)(bh * 64 + row)) * TT + s0 + cg * 8,
              &Vs[(r * 256 + wv * 64) * 8]);
    }
    // mask loads for this tile (32 KB total: L2-resident after first touch)
    f32x4 mL[4];
    for (int ct = 0; ct < 4; ++ct)
      mL[ct] = *(const f32x4*)(mrow + s0 + ct * 16);
    __syncthreads();  // drains vmcnt(0): staged tiles + bL/mL complete

    // S^T = K @ Q^T : row = s (ct*16+quad*4+reg), col = q (l16)
    f32x4 sacc[4];
    for (int ct = 0; ct < 4; ++ct) sacc[ct] = (f32x4){0.f, 0.f, 0.f, 0.f};
    __builtin_amdgcn_s_setprio(1);
    for (int kc = 0; kc < 2; ++kc) {
      half8 kf[4];
      for (int ct = 0; ct < 4; ++ct) {
        int row = ct * 16 + l16;
        int c = (kc * 4 + quad) ^ (row & 7);
        kf[ct] = *(const half8*)&Ks[row * 64 + c * 8];
      }
      for (int ct = 0; ct < 4; ++ct)
        sacc[ct] = __builtin_amdgcn_mfma_f32_16x16x32_f16(kf[ct], qf[kc],
                                                          sacc[ct], 0, 0, 0);
    }
    __builtin_amdgcn_s_setprio(0);

    // s-values for this lane's q-row
    float sv[4][4];
    for (int ct = 0; ct < 4; ++ct)
      for (int reg = 0; reg < 4; ++reg)
        sv[ct][reg] = sacc[ct][reg] + bL[ct][reg] + mL[ct][reg];

    // prefetch bias for the NEXT tile (wraps to 0 at the end; harmless)
    {
      int sn = (st < 31) ? s0 + 64 : 0;
      for (int ct = 0; ct < 4; ++ct)
        bL[ct] = *(const f32x4*)(brow + sn + ct * 16);
    }

    // Online softmax: stats are lane-local (one q-row per lane).
    float mc[4];
    for (int ct = 0; ct < 4; ++ct)
      mc[ct] = fmaxf(fmaxf(sv[ct][0], sv[ct][1]), fmaxf(sv[ct][2], sv[ct][3]));
    float mx = fmaxf(fmaxf(mc[0], mc[1]), fmaxf(mc[2], mc[3]));
    mx = fmaxf(mx, __shfl_xor(mx, 16));
    mx = fmaxf(mx, __shfl_xor(mx, 32));
    float mnew = fmaxf(m_i, mx);
    float alpha = __builtin_amdgcn_exp2f((m_i - mnew) * L2E);
    float nl2e = mnew * L2E;
    float rs = 0.f;
    for (int ct = 0; ct < 4; ++ct)
      for (int reg = 0; reg < 4; ++reg) {
        float p = __builtin_amdgcn_exp2f(sv[ct][reg] * L2E - nl2e);
        sv[ct][reg] = p;
        rs += p;
      }
    rs += __shfl_xor(rs, 16);
    rs += __shfl_xor(rs, 32);
    l_i = l_i * alpha + rs;
    m_i = mnew;
    for (int ct = 0; ct < 4; ++ct) {
      oacc[ct][0] *= alpha; oacc[ct][1] *= alpha;
      oacc[ct][2] *= alpha; oacc[ct][3] *= alpha;
    }

    // Pack P -> LDS: row = wv*16+l16 (q, wave-private), 4 halfs per b64 write.
    for (int ct = 0; ct < 4; ++ct) {
      uint2 pk;
      pk.x = (unsigned)f2h(sv[ct][0]) | ((unsigned)f2h(sv[ct][1]) << 16);
      pk.y = (unsigned)f2h(sv[ct][2]) | ((unsigned)f2h(sv[ct][3]) << 16);
      *(uint2*)&Pl[(wv * 16 + l16) * 72 + ct * 16 + quad * 4] = pk;
    }
    // P rows are written and read by the SAME wave: a wave-local LDS drain
    // replaces the block barrier here.
    asm volatile("s_waitcnt lgkmcnt(0)" ::: "memory");
    __builtin_amdgcn_sched_barrier(0);

    // O^T += V^T @ P^T : row = dk (ct*16+quad*4+reg), col = q (l16)
    __builtin_amdgcn_s_setprio(1);
    for (int kc = 0; kc < 2; ++kc) {
      half8 pf = *(const half8*)&Pl[(wv * 16 + l16) * 72 + kc * 32 + quad * 8];
      half8 vf[4];
      for (int ct = 0; ct < 4; ++ct) {
        int row = ct * 16 + l16;
        int c = (kc * 4 + quad) ^ (row & 7);
        vf[ct] = *(const half8*)&Vs[row * 64 + c * 8];
      }
      for (int ct = 0; ct < 4; ++ct)
        oacc[ct] = __builtin_amdgcn_mfma_f32_16x16x32_f16(vf[ct], pf,
                                                          oacc[ct], 0, 0, 0);
    }
    __builtin_amdgcn_s_setprio(0);
    __syncthreads();  // protect Ks/Vs before next tile's staging
  }

  // Epilogue: lane holds O[dk = ct*16+quad*4+reg][q = qrow]; 1/l is lane-local.
  float inv = 1.f / l_i;
  size_t ybase = ((size_t)(b * TT + qrow)) * DIM + h * 64 + quad * 4;
  for (int ct = 0; ct < 4; ++ct) {
    uint2 pk;
    pk.x = (unsigned)f2h(oacc[ct][0] * inv) |
           ((unsigned)f2h(oacc[ct][1] * inv) << 16);
    pk.y = (unsigned)f2h(oacc[ct][2] * inv) |
           ((unsigned)f2h(oacc[ct][3] * inv) << 16);
    *(uint2*)(Y + ybase + ct * 16) = pk;
  }
}

extern "C" void kernel_launch(void* const* d_in, const int* in_sizes, int n_in,
                              void* d_out, int out_size, void* d_ws, size_t ws_size,
                              hipStream_t stream) {
  const float* x    = (const float*)d_in[0];
  const float* mask = (const float*)d_in[1];
  const float* bias = (const float*)d_in[2];
  const float* Wq   = (const float*)d_in[3];
  const float* Wk   = (const float*)d_in[4];
  const float* Wv   = (const float*)d_in[5];
  const float* Wo   = (const float*)d_in[6];
  (void)Wk; (void)Wv;  // consumed via contiguous weight block in ws

  // Workspace (f16 elems): xb | wq,wk,wv,wo | Q,K,Vt | y  (~44 MB)
  u16* xb  = (u16*)d_ws;
  u16* wb  = xb + 4194304;            // 4 * 262144
  u16* qkv = wb + 4 * 262144;         // Q, K head-major; V^T
  u16* yb  = qkv + 3 * (size_t)4194304;

  k_convert<<<2560, 256, 0, stream>>>(x, Wq, Wk, Wv, Wo, xb);
  k_proj<false><<<dim3(64, 4, 2), 256, 0, stream>>>(xb, wb, qkv);
  k_proj<true><<<dim3(64, 4), 256, 0, stream>>>(xb, wb, qkv);
  k_attn<<<1024, 256, 0, stream>>>(qkv, qkv + 4194304,
                                   qkv + 2 * (size_t)4194304, bias, mask, yb);
  k_ogemm<<<dim3(128, 4), 256, 0, stream>>>(yb, wb + 3 * 262144, (float*)d_out);
}